// Round 1
// baseline (362.071 us; speedup 1.0000x reference)
//
#include <hip/hip_runtime.h>
#include <math.h>

namespace {

constexpr int C_  = 16;
constexpr int OR_ = 8;
constexpr int H_  = 192;
constexpr int W_  = 192;
constexpr int HW_ = H_ * W_;
constexpr int CH_ = OR_ * HW_;
constexpr float PI_F = 3.14159265358979323846f;

// Zero-padded corner fetch (matches reference _sample's per-corner validity).
__device__ __forceinline__ float corner(const float* __restrict__ p, int iy, int ix) {
    bool valid = ((unsigned)iy < (unsigned)H_) && ((unsigned)ix < (unsigned)W_);
    int yc = min(max(iy, 0), H_ - 1);
    int xc = min(max(ix, 0), W_ - 1);
    float v = p[yc * W_ + xc];
    return valid ? v : 0.0f;
}

// ---------------- convection_m2 ----------------
// out[c,th,y,x] = trilinear sample of u at (th - th0, (x,y) - R(th-th0)(x0,y0)),
// periodic in orientation, zero-padded spatially.
__global__ __launch_bounds__(256) void conv_kernel(
        const float* __restrict__ u, const float* __restrict__ g0,
        float* __restrict__ out) {
    const int x = blockIdx.x * 64 + (threadIdx.x & 63);
    const int y = blockIdx.y * 4 + (threadIdx.x >> 6);
    const int z = blockIdx.z;
    const int c  = z >> 3;
    const int th = z & 7;

    const float gx0  = g0[c * 3 + 0];
    const float gy0  = g0[c * 3 + 1];
    const float gth0 = g0[c * 3 + 2];

    const float a = (float)th * (2.0f * PI_F / OR_) - gth0;
    float sa, ca;
    sincosf(a, &sa, &ca);
    const float dxs = ca * gx0 - sa * gy0;
    const float dys = sa * gx0 + ca * gy0;

    const float fx = (float)x - dxs;
    const float fy = (float)y - dys;
    const float fx0 = floorf(fx), fy0 = floorf(fy);
    const float wx = fx - fx0, wy = fy - fy0;
    const int ix0 = (int)fx0, iy0 = (int)fy0;

    // orientation blend: tc = (th - th0*Or/(2pi)) mod Or
    float tc = (float)th - gth0 * (OR_ / (2.0f * PI_F));
    tc = tc - floorf(tc * (1.0f / OR_)) * (float)OR_;
    const float t0f = floorf(tc);
    const float wt = tc - t0f;
    const int t0i = ((int)t0f) & 7;   // handles tc==8.0 edge
    const int t1i = (t0i + 1) & 7;

    const float w00 = (1.f - wy) * (1.f - wx);
    const float w01 = (1.f - wy) * wx;
    const float w10 = wy * (1.f - wx);
    const float w11 = wy * wx;

    const float* __restrict__ p0 = u + c * CH_ + t0i * HW_;
    const float* __restrict__ p1 = u + c * CH_ + t1i * HW_;

    float v0, v1;
    if (ix0 >= 0 && ix0 + 1 < W_ && iy0 >= 0 && iy0 + 1 < H_) {
        const int o = iy0 * W_ + ix0;
        v0 = w00 * p0[o] + w01 * p0[o + 1] + w10 * p0[o + W_] + w11 * p0[o + W_ + 1];
        v1 = w00 * p1[o] + w01 * p1[o + 1] + w10 * p1[o + W_] + w11 * p1[o + W_ + 1];
    } else {
        v0 = w00 * corner(p0, iy0, ix0)     + w01 * corner(p0, iy0, ix0 + 1)
           + w10 * corner(p0, iy0 + 1, ix0) + w11 * corner(p0, iy0 + 1, ix0 + 1);
        v1 = w00 * corner(p1, iy0, ix0)     + w01 * corner(p1, iy0, ix0 + 1)
           + w10 * corner(p1, iy0 + 1, ix0) + w11 * corner(p1, iy0 + 1, ix0 + 1);
    }
    out[c * CH_ + th * HW_ + y * W_ + x] = (1.f - wt) * v0 + wt * v1;
}

// ---------------- fractional_dilation_m2 ----------------
// out[c,th,y,x] = max over 27 offsets (hti,hy,hx) of
//   bilinear(u[c, (th+hti)&7], (y,x) + R(th)(hx,hy)) - kcost(c, offset)
__global__ __launch_bounds__(256) void dil_kernel(
        const float* __restrict__ u, const float* __restrict__ mp,
        float* __restrict__ out) {
    __shared__ int   s_rel[27];     // plane*HW + dy*W + dx  (relative address)
    __shared__ float s_w00[27], s_w01[27], s_w10[27], s_w11[27], s_k[27];
    __shared__ int   s_dx[27], s_dy[27], s_plane[27];

    const int z = blockIdx.z;
    const int c  = z >> 3;
    const int th = z & 7;

    const int t = threadIdx.x;
    if (t < 27) {
        const int hti = t / 9 - 1;
        const int hyi = (t / 3) % 3 - 1;
        const int hxi = t % 3 - 1;
        const float hx = (float)hxi, hy = (float)hyi;

        // kernel cost from SE(2) log-coordinates
        const float hth  = (float)hti * (2.0f * PI_F / OR_);
        const float half = 0.5f * hth;
        float q;
        if (fabsf(half) < 1e-4f) q = 1.0f - half * half * (1.0f / 3.0f);
        else                     q = half / tanf(half);
        const float c1 = q * hx + half * hy;
        const float c2 = -half * hx + q * hy;
        const float c3 = hth;
        const float m0 = mp[c * 3 + 0], m1 = mp[c * 3 + 1], m2 = mp[c * 3 + 2];
        const float d2 = (m0 * c1) * (m0 * c1) + (m1 * c2) * (m1 * c2) + (m2 * c3) * (m2 * c3);
        const float ee = 2.0f * 0.65f / (2.0f * 0.65f - 1.0f);      // 4.333333
        const float nu = (2.0f * 0.65f - 1.0f) * powf(2.0f * 0.65f, -ee);
        const float kc = nu * powf(d2, 0.5f * ee);                  // 0 when d2==0

        // rotated spatial offset (depends only on th, offset)
        const float theta = (float)th * (2.0f * PI_F / OR_);
        float st, ct;
        sincosf(theta, &st, &ct);
        const float sx = ct * hx - st * hy;
        const float sy = st * hx + ct * hy;
        const float fx0 = floorf(sx), fy0 = floorf(sy);
        const float wx = sx - fx0, wy = sy - fy0;
        const int dx = (int)fx0, dy = (int)fy0;
        const int plane = (th + hti + OR_) & 7;

        s_rel[t]   = plane * HW_ + dy * W_ + dx;
        s_w00[t]   = (1.f - wy) * (1.f - wx);
        s_w01[t]   = (1.f - wy) * wx;
        s_w10[t]   = wy * (1.f - wx);
        s_w11[t]   = wy * wx;
        s_k[t]     = kc;
        s_dx[t]    = dx;
        s_dy[t]    = dy;
        s_plane[t] = plane;
    }
    __syncthreads();

    const int x = blockIdx.x * 64 + (threadIdx.x & 63);
    const int y = blockIdx.y * 4 + (threadIdx.x >> 6);
    const int pix = y * W_ + x;
    const float* __restrict__ base = u + c * CH_;

    float acc = -INFINITY;
    // |rotated offset| <= sqrt(2) -> dx,dy in [-2,1]; interior needs x,y in [2, 189]
    const bool interior = (x >= 2) && (x <= W_ - 3) && (y >= 2) && (y <= H_ - 3);
    if (interior) {
        #pragma unroll
        for (int o = 0; o < 27; ++o) {
            const float* __restrict__ p = base + pix + s_rel[o];
            const float v = s_w00[o] * p[0]  + s_w01[o] * p[1]
                          + s_w10[o] * p[W_] + s_w11[o] * p[W_ + 1];
            acc = fmaxf(acc, v - s_k[o]);
        }
    } else {
        for (int o = 0; o < 27; ++o) {
            const int ix = x + s_dx[o];
            const int iy = y + s_dy[o];
            const float* __restrict__ p = base + s_plane[o] * HW_;
            const float v = s_w00[o] * corner(p, iy, ix)
                          + s_w01[o] * corner(p, iy, ix + 1)
                          + s_w10[o] * corner(p, iy + 1, ix)
                          + s_w11[o] * corner(p, iy + 1, ix + 1);
            acc = fmaxf(acc, v - s_k[o]);
        }
    }
    out[c * CH_ + th * HW_ + pix] = acc;
}

} // anonymous namespace

extern "C" void kernel_launch(void* const* d_in, const int* in_sizes, int n_in,
                              void* d_out, int out_size, void* d_ws, size_t ws_size,
                              hipStream_t stream) {
    const float* u   = (const float*)d_in[0];
    const float* g0  = (const float*)d_in[1];
    const float* mpp = (const float*)d_in[2];
    float* out = (float*)d_out;
    float* ws  = (float*)d_ws;   // one [C,Or,H,W] f32 buffer = 18.9 MB

    dim3 grid(W_ / 64, H_ / 4, C_ * OR_);
    dim3 block(256);

    // iter 1
    conv_kernel<<<grid, block, 0, stream>>>(u,   g0,  ws);
    dil_kernel <<<grid, block, 0, stream>>>(ws,  mpp, out);
    // iter 2
    conv_kernel<<<grid, block, 0, stream>>>(out, g0,  ws);
    dil_kernel <<<grid, block, 0, stream>>>(ws,  mpp, out);
}

// Round 2
// 104.518 us; speedup vs baseline: 3.4642x; 3.4642x over previous
//
#include <hip/hip_runtime.h>
#include <math.h>

namespace {

constexpr int C_  = 16;
constexpr int OR_ = 8;
constexpr int H_  = 192;
constexpr int W_  = 192;
constexpr int HW_ = H_ * W_;
constexpr int CH_ = OR_ * HW_;
constexpr float PI_F = 3.14159265358979323846f;

// LDS tile geometry for dilation: 64x16 output tile, halo 2 each side, 3 planes.
constexpr int TW_ = 68;               // 64 + 2*2
constexpr int TR_ = 20;               // 16 + 2*2
constexpr int TSZ_ = 3 * TR_ * TW_;   // 4080 floats

// Zero-padded corner fetch (matches reference _sample's per-corner validity).
__device__ __forceinline__ float corner(const float* __restrict__ p, int iy, int ix) {
    bool valid = ((unsigned)iy < (unsigned)H_) && ((unsigned)ix < (unsigned)W_);
    int yc = min(max(iy, 0), H_ - 1);
    int xc = min(max(ix, 0), W_ - 1);
    float v = p[yc * W_ + xc];
    return valid ? v : 0.0f;
}

// ---------------- convection_m2 ----------------
// out[c,th,y,x] = trilinear sample of u at (th - th0, (x,y) - R(th-th0)(x0,y0)).
// 4 pixels per thread along y (shared column loads), 64x16 tile per block.
__global__ __launch_bounds__(256) void conv_kernel(
        const float* __restrict__ u, const float* __restrict__ g0,
        float* __restrict__ out) {
    const int tx  = threadIdx.x & 63;
    const int ty0 = (threadIdx.x >> 6) * 4;
    const int x   = blockIdx.x * 64 + tx;
    const int y0  = blockIdx.y * 16 + ty0;
    const int z = blockIdx.z;
    const int c  = z >> 3;
    const int th = z & 7;

    const float gx0  = g0[c * 3 + 0];
    const float gy0  = g0[c * 3 + 1];
    const float gth0 = g0[c * 3 + 2];

    const float a = (float)th * (2.0f * PI_F / OR_) - gth0;
    float sa, ca;
    sincosf(a, &sa, &ca);
    const float dxs = ca * gx0 - sa * gy0;
    const float dys = sa * gx0 + ca * gy0;

    const float fx = (float)x - dxs;
    const float fy = (float)y0 - dys;
    const float fx0 = floorf(fx), fy0 = floorf(fy);
    const float wx = fx - fx0, wy = fy - fy0;
    const int ix0 = (int)fx0, iy0 = (int)fy0;

    float tc = (float)th - gth0 * (OR_ / (2.0f * PI_F));
    tc = tc - floorf(tc * (1.0f / OR_)) * (float)OR_;
    const float t0f = floorf(tc);
    const float wt = tc - t0f;
    const int t0i = ((int)t0f) & 7;
    const int t1i = (t0i + 1) & 7;

    const float* __restrict__ p0 = u + c * CH_ + t0i * HW_;
    const float* __restrict__ p1 = u + c * CH_ + t1i * HW_;

    float r0, r1, r2, r3;
    if (ix0 >= 0 && ix0 + 1 < W_ && iy0 >= 0 && iy0 + 4 < H_) {
        const int o = iy0 * W_ + ix0;
        // plane t0: 5 rows x 2 cols
        float a00 = p0[o],          a01 = p0[o + 1];
        float a10 = p0[o + W_],     a11 = p0[o + W_ + 1];
        float a20 = p0[o + 2 * W_], a21 = p0[o + 2 * W_ + 1];
        float a30 = p0[o + 3 * W_], a31 = p0[o + 3 * W_ + 1];
        float a40 = p0[o + 4 * W_], a41 = p0[o + 4 * W_ + 1];
        float b00 = p1[o],          b01 = p1[o + 1];
        float b10 = p1[o + W_],     b11 = p1[o + W_ + 1];
        float b20 = p1[o + 2 * W_], b21 = p1[o + 2 * W_ + 1];
        float b30 = p1[o + 3 * W_], b31 = p1[o + 3 * W_ + 1];
        float b40 = p1[o + 4 * W_], b41 = p1[o + 4 * W_ + 1];
        float ha0 = a00 + wx * (a01 - a00);
        float ha1 = a10 + wx * (a11 - a10);
        float ha2 = a20 + wx * (a21 - a20);
        float ha3 = a30 + wx * (a31 - a30);
        float ha4 = a40 + wx * (a41 - a40);
        float hb0 = b00 + wx * (b01 - b00);
        float hb1 = b10 + wx * (b11 - b10);
        float hb2 = b20 + wx * (b21 - b20);
        float hb3 = b30 + wx * (b31 - b30);
        float hb4 = b40 + wx * (b41 - b40);
        float va0 = ha0 + wy * (ha1 - ha0);
        float va1 = ha1 + wy * (ha2 - ha1);
        float va2 = ha2 + wy * (ha3 - ha2);
        float va3 = ha3 + wy * (ha4 - ha3);
        float vb0 = hb0 + wy * (hb1 - hb0);
        float vb1 = hb1 + wy * (hb2 - hb1);
        float vb2 = hb2 + wy * (hb3 - hb2);
        float vb3 = hb3 + wy * (hb4 - hb3);
        r0 = va0 + wt * (vb0 - va0);
        r1 = va1 + wt * (vb1 - va1);
        r2 = va2 + wt * (vb2 - va2);
        r3 = va3 + wt * (vb3 - va3);
    } else {
        const float w00 = (1.f - wy) * (1.f - wx);
        const float w01 = (1.f - wy) * wx;
        const float w10 = wy * (1.f - wx);
        const float w11 = wy * wx;
        float rr[4];
        #pragma unroll
        for (int j = 0; j < 4; ++j) {
            const int iy = iy0 + j;
            float v0 = w00 * corner(p0, iy, ix0)     + w01 * corner(p0, iy, ix0 + 1)
                     + w10 * corner(p0, iy + 1, ix0) + w11 * corner(p0, iy + 1, ix0 + 1);
            float v1 = w00 * corner(p1, iy, ix0)     + w01 * corner(p1, iy, ix0 + 1)
                     + w10 * corner(p1, iy + 1, ix0) + w11 * corner(p1, iy + 1, ix0 + 1);
            rr[j] = v0 + wt * (v1 - v0);
        }
        r0 = rr[0]; r1 = rr[1]; r2 = rr[2]; r3 = rr[3];
    }
    float* __restrict__ op = out + c * CH_ + th * HW_ + y0 * W_ + x;
    op[0]      = r0;
    op[W_]     = r1;
    op[2 * W_] = r2;
    op[3 * W_] = r3;
}

// ---------------- fractional_dilation_m2 ----------------
// LDS-staged: 3 orientation planes (th-1,th,th+1), 64x16 tile + halo 2,
// zero-padded (matches reference zero-pad => no border special case).
// 4 pixels per thread along y; 10 ds_reads per offset serve 4 outputs.
__global__ __launch_bounds__(256) void dil_kernel(
        const float* __restrict__ u, const float* __restrict__ mp,
        float* __restrict__ out) {
    __shared__ float tile[TSZ_];
    __shared__ int   s_rel[27];
    __shared__ float s_wx[27], s_wy[27], s_k[27];

    const int z = blockIdx.z;
    const int c  = z >> 3;
    const int th = z & 7;
    const int t = threadIdx.x;

    if (t < 27) {
        const int hti = t / 9 - 1;
        const int hyi = (t / 3) % 3 - 1;
        const int hxi = t % 3 - 1;
        const float hx = (float)hxi, hy = (float)hyi;

        const float hth  = (float)hti * (2.0f * PI_F / OR_);
        const float half = 0.5f * hth;
        float q;
        if (fabsf(half) < 1e-4f) q = 1.0f - half * half * (1.0f / 3.0f);
        else                     q = half / tanf(half);
        const float c1 = q * hx + half * hy;
        const float c2 = -half * hx + q * hy;
        const float c3 = hth;
        const float m0 = mp[c * 3 + 0], m1 = mp[c * 3 + 1], m2 = mp[c * 3 + 2];
        const float d2 = (m0 * c1) * (m0 * c1) + (m1 * c2) * (m1 * c2) + (m2 * c3) * (m2 * c3);
        const float ee = 2.0f * 0.65f / (2.0f * 0.65f - 1.0f);
        const float nu = (2.0f * 0.65f - 1.0f) * powf(2.0f * 0.65f, -ee);
        const float kc = nu * powf(d2, 0.5f * ee);

        const float theta = (float)th * (2.0f * PI_F / OR_);
        float st, ct;
        sincosf(theta, &st, &ct);
        const float sx = ct * hx - st * hy;
        const float sy = st * hx + ct * hy;
        const float fx0 = floorf(sx), fy0 = floorf(sy);
        s_wx[t] = sx - fx0;
        s_wy[t] = sy - fy0;
        s_k[t]  = kc;
        // dword offset inside LDS tile relative to a thread's (plane0, y_local+2, x_local+2)
        s_rel[t] = ((hti + 1) * TR_ + (int)fy0) * TW_ + (int)fx0;
    }

    // stage 3 planes with halo, zero-padded outside image
    const int bx0 = blockIdx.x * 64 - 2;
    const int by0 = blockIdx.y * 16 - 2;
    const float* __restrict__ base = u + c * CH_;
    for (int i = t; i < TSZ_; i += 256) {
        const int r   = i / TW_;
        const int col = i - r * TW_;
        const int p   = r / TR_;
        const int rr  = r - p * TR_;
        const int gy = by0 + rr;
        const int gx = bx0 + col;
        const int plane = (th + p - 1 + OR_) & 7;
        float v = 0.0f;
        if ((unsigned)gy < (unsigned)H_ && (unsigned)gx < (unsigned)W_)
            v = base[plane * HW_ + gy * W_ + gx];
        tile[i] = v;
    }
    __syncthreads();

    const int tx  = t & 63;
    const int ty0 = (t >> 6) * 4;
    const int lb = (ty0 + 2) * TW_ + tx + 2;

    float a0 = -INFINITY, a1 = -INFINITY, a2 = -INFINITY, a3 = -INFINITY;
    #pragma unroll
    for (int o = 0; o < 27; ++o) {
        const int ad = lb + s_rel[o];
        const float wx = s_wx[o], wy = s_wy[o], k = s_k[o];
        const float c00 = tile[ad],            c01 = tile[ad + 1];
        const float c10 = tile[ad + TW_],      c11 = tile[ad + TW_ + 1];
        const float c20 = tile[ad + 2 * TW_],  c21 = tile[ad + 2 * TW_ + 1];
        const float c30 = tile[ad + 3 * TW_],  c31 = tile[ad + 3 * TW_ + 1];
        const float c40 = tile[ad + 4 * TW_],  c41 = tile[ad + 4 * TW_ + 1];
        const float h0 = c00 + wx * (c01 - c00);
        const float h1 = c10 + wx * (c11 - c10);
        const float h2 = c20 + wx * (c21 - c20);
        const float h3 = c30 + wx * (c31 - c30);
        const float h4 = c40 + wx * (c41 - c40);
        const float v0 = h0 + wy * (h1 - h0);
        const float v1 = h1 + wy * (h2 - h1);
        const float v2 = h2 + wy * (h3 - h2);
        const float v3 = h3 + wy * (h4 - h3);
        a0 = fmaxf(a0, v0 - k);
        a1 = fmaxf(a1, v1 - k);
        a2 = fmaxf(a2, v2 - k);
        a3 = fmaxf(a3, v3 - k);
    }

    const int x = blockIdx.x * 64 + tx;
    const int y = blockIdx.y * 16 + ty0;
    float* __restrict__ op = out + c * CH_ + th * HW_ + y * W_ + x;
    op[0]      = a0;
    op[W_]     = a1;
    op[2 * W_] = a2;
    op[3 * W_] = a3;
}

} // anonymous namespace

extern "C" void kernel_launch(void* const* d_in, const int* in_sizes, int n_in,
                              void* d_out, int out_size, void* d_ws, size_t ws_size,
                              hipStream_t stream) {
    const float* u   = (const float*)d_in[0];
    const float* g0  = (const float*)d_in[1];
    const float* mpp = (const float*)d_in[2];
    float* out = (float*)d_out;
    float* ws  = (float*)d_ws;

    dim3 grid(W_ / 64, H_ / 16, C_ * OR_);
    dim3 block(256);

    conv_kernel<<<grid, block, 0, stream>>>(u,   g0,  ws);
    dil_kernel <<<grid, block, 0, stream>>>(ws,  mpp, out);
    conv_kernel<<<grid, block, 0, stream>>>(out, g0,  ws);
    dil_kernel <<<grid, block, 0, stream>>>(ws,  mpp, out);
}

// Round 3
// 89.342 us; speedup vs baseline: 4.0526x; 1.1699x over previous
//
#include <hip/hip_runtime.h>
#include <math.h>
#include <utility>

namespace {

constexpr int C_  = 16;
constexpr int OR_ = 8;
constexpr int H_  = 192;
constexpr int W_  = 192;
constexpr int HW_ = H_ * W_;
constexpr int CH_ = OR_ * HW_;
constexpr float PI_F = 3.14159265358979323846f;

// LDS tile geometry for dilation: 64x16 output tile, halo 2 each side, 3 planes.
constexpr int TW_ = 68;               // 64 + 2*2
constexpr int TR_ = 20;               // 16 + 2*2
constexpr int TSZ_ = 3 * TR_ * TW_;   // 4080 floats

// cos/sin of th*pi/4, exact constants (f32-rounded identical to reference within 1e-7).
constexpr float SQ2H = 0.70710678118654752440f;
constexpr float CT8[8] = { 1.0f,  SQ2H,  0.0f, -SQ2H, -1.0f, -SQ2H,  0.0f,  SQ2H };
constexpr float ST8[8] = { 0.0f,  SQ2H,  1.0f,  SQ2H,  0.0f, -SQ2H, -1.0f, -SQ2H };

constexpr int cfloor(float v) {
    return (v >= 0.0f) ? (int)v : (((float)(int)v == v) ? (int)v : (int)v - 1);
}

// Zero-padded corner fetch (matches reference _sample's per-corner validity).
__device__ __forceinline__ float corner(const float* __restrict__ p, int iy, int ix) {
    bool valid = ((unsigned)iy < (unsigned)H_) && ((unsigned)ix < (unsigned)W_);
    int yc = min(max(iy, 0), H_ - 1);
    int xc = min(max(ix, 0), W_ - 1);
    float v = p[yc * W_ + xc];
    return valid ? v : 0.0f;
}

// ---------------- convection_m2 ----------------
__global__ __launch_bounds__(256) void conv_kernel(
        const float* __restrict__ u, const float* __restrict__ g0,
        float* __restrict__ out) {
    const int tx  = threadIdx.x & 63;
    const int ty0 = (threadIdx.x >> 6) * 4;
    const int x   = blockIdx.x * 64 + tx;
    const int y0  = blockIdx.y * 16 + ty0;
    const int z = blockIdx.z;
    const int c  = z >> 3;
    const int th = z & 7;

    const float gx0  = g0[c * 3 + 0];
    const float gy0  = g0[c * 3 + 1];
    const float gth0 = g0[c * 3 + 2];

    const float a = (float)th * (2.0f * PI_F / OR_) - gth0;
    float sa, ca;
    sincosf(a, &sa, &ca);
    const float dxs = ca * gx0 - sa * gy0;
    const float dys = sa * gx0 + ca * gy0;

    const float fx = (float)x - dxs;
    const float fy = (float)y0 - dys;
    const float fx0 = floorf(fx), fy0 = floorf(fy);
    const float wx = fx - fx0, wy = fy - fy0;
    const int ix0 = (int)fx0, iy0 = (int)fy0;

    float tc = (float)th - gth0 * (OR_ / (2.0f * PI_F));
    tc = tc - floorf(tc * (1.0f / OR_)) * (float)OR_;
    const float t0f = floorf(tc);
    const float wt = tc - t0f;
    const int t0i = ((int)t0f) & 7;
    const int t1i = (t0i + 1) & 7;

    const float* __restrict__ p0 = u + c * CH_ + t0i * HW_;
    const float* __restrict__ p1 = u + c * CH_ + t1i * HW_;

    float r0, r1, r2, r3;
    if (ix0 >= 0 && ix0 + 1 < W_ && iy0 >= 0 && iy0 + 4 < H_) {
        const int o = iy0 * W_ + ix0;
        float a00 = p0[o],          a01 = p0[o + 1];
        float a10 = p0[o + W_],     a11 = p0[o + W_ + 1];
        float a20 = p0[o + 2 * W_], a21 = p0[o + 2 * W_ + 1];
        float a30 = p0[o + 3 * W_], a31 = p0[o + 3 * W_ + 1];
        float a40 = p0[o + 4 * W_], a41 = p0[o + 4 * W_ + 1];
        float b00 = p1[o],          b01 = p1[o + 1];
        float b10 = p1[o + W_],     b11 = p1[o + W_ + 1];
        float b20 = p1[o + 2 * W_], b21 = p1[o + 2 * W_ + 1];
        float b30 = p1[o + 3 * W_], b31 = p1[o + 3 * W_ + 1];
        float b40 = p1[o + 4 * W_], b41 = p1[o + 4 * W_ + 1];
        float ha0 = a00 + wx * (a01 - a00);
        float ha1 = a10 + wx * (a11 - a10);
        float ha2 = a20 + wx * (a21 - a20);
        float ha3 = a30 + wx * (a31 - a30);
        float ha4 = a40 + wx * (a41 - a40);
        float hb0 = b00 + wx * (b01 - b00);
        float hb1 = b10 + wx * (b11 - b10);
        float hb2 = b20 + wx * (b21 - b20);
        float hb3 = b30 + wx * (b31 - b30);
        float hb4 = b40 + wx * (b41 - b40);
        float va0 = ha0 + wy * (ha1 - ha0);
        float va1 = ha1 + wy * (ha2 - ha1);
        float va2 = ha2 + wy * (ha3 - ha2);
        float va3 = ha3 + wy * (ha4 - ha3);
        float vb0 = hb0 + wy * (hb1 - hb0);
        float vb1 = hb1 + wy * (hb2 - hb1);
        float vb2 = hb2 + wy * (hb3 - hb2);
        float vb3 = hb3 + wy * (hb4 - hb3);
        r0 = va0 + wt * (vb0 - va0);
        r1 = va1 + wt * (vb1 - va1);
        r2 = va2 + wt * (vb2 - va2);
        r3 = va3 + wt * (vb3 - va3);
    } else {
        const float w00 = (1.f - wy) * (1.f - wx);
        const float w01 = (1.f - wy) * wx;
        const float w10 = wy * (1.f - wx);
        const float w11 = wy * wx;
        float rr[4];
        #pragma unroll
        for (int j = 0; j < 4; ++j) {
            const int iy = iy0 + j;
            float v0 = w00 * corner(p0, iy, ix0)     + w01 * corner(p0, iy, ix0 + 1)
                     + w10 * corner(p0, iy + 1, ix0) + w11 * corner(p0, iy + 1, ix0 + 1);
            float v1 = w00 * corner(p1, iy, ix0)     + w01 * corner(p1, iy, ix0 + 1)
                     + w10 * corner(p1, iy + 1, ix0) + w11 * corner(p1, iy + 1, ix0 + 1);
            rr[j] = v0 + wt * (v1 - v0);
        }
        r0 = rr[0]; r1 = rr[1]; r2 = rr[2]; r3 = rr[3];
    }
    float* __restrict__ op = out + c * CH_ + th * HW_ + y0 * W_ + x;
    op[0]      = r0;
    op[W_]     = r1;
    op[2 * W_] = r2;
    op[3 * W_] = r3;
}

// ---------------- fractional_dilation_m2 (TH compile-time) ----------------
// All sampling geometry (dx,dy,wx,wy,rel) is constexpr per (TH, offset):
// even TH -> exact integer shifts (1 read/px/offset); odd TH -> half the
// offsets have wx==0 or wy==0. Addresses become base+immediate -> CSE.
template<int TH, int O>
__device__ __forceinline__ void dil_one(const float* __restrict__ tile,
                                        const float* __restrict__ sk, int lb,
                                        float& a0, float& a1, float& a2, float& a3) {
    constexpr int hti = O / 9 - 1;
    constexpr int hyi = (O / 3) % 3 - 1;
    constexpr int hxi = O % 3 - 1;
    constexpr float ct = CT8[TH];
    constexpr float st = ST8[TH];
    constexpr float sx = ct * (float)hxi - st * (float)hyi;
    constexpr float sy = st * (float)hxi + ct * (float)hyi;
    constexpr int dx = cfloor(sx);
    constexpr int dy = cfloor(sy);
    constexpr float wx = sx - (float)dx;
    constexpr float wy = sy - (float)dy;
    constexpr int rel = ((hti + 1) * TR_ + dy) * TW_ + dx;

    const float k = sk[O];
    const int ad = lb + rel;
    float v0, v1, v2, v3;
    if constexpr (wx == 0.0f && wy == 0.0f) {
        v0 = tile[ad];
        v1 = tile[ad + TW_];
        v2 = tile[ad + 2 * TW_];
        v3 = tile[ad + 3 * TW_];
    } else if constexpr (wy == 0.0f) {
        float c00 = tile[ad],           c01 = tile[ad + 1];
        float c10 = tile[ad + TW_],     c11 = tile[ad + TW_ + 1];
        float c20 = tile[ad + 2 * TW_], c21 = tile[ad + 2 * TW_ + 1];
        float c30 = tile[ad + 3 * TW_], c31 = tile[ad + 3 * TW_ + 1];
        v0 = c00 + wx * (c01 - c00);
        v1 = c10 + wx * (c11 - c10);
        v2 = c20 + wx * (c21 - c20);
        v3 = c30 + wx * (c31 - c30);
    } else if constexpr (wx == 0.0f) {
        float c0 = tile[ad];
        float c1 = tile[ad + TW_];
        float c2 = tile[ad + 2 * TW_];
        float c3 = tile[ad + 3 * TW_];
        float c4 = tile[ad + 4 * TW_];
        v0 = c0 + wy * (c1 - c0);
        v1 = c1 + wy * (c2 - c1);
        v2 = c2 + wy * (c3 - c2);
        v3 = c3 + wy * (c4 - c3);
    } else {
        float c00 = tile[ad],           c01 = tile[ad + 1];
        float c10 = tile[ad + TW_],     c11 = tile[ad + TW_ + 1];
        float c20 = tile[ad + 2 * TW_], c21 = tile[ad + 2 * TW_ + 1];
        float c30 = tile[ad + 3 * TW_], c31 = tile[ad + 3 * TW_ + 1];
        float c40 = tile[ad + 4 * TW_], c41 = tile[ad + 4 * TW_ + 1];
        float h0 = c00 + wx * (c01 - c00);
        float h1 = c10 + wx * (c11 - c10);
        float h2 = c20 + wx * (c21 - c20);
        float h3 = c30 + wx * (c31 - c30);
        float h4 = c40 + wx * (c41 - c40);
        v0 = h0 + wy * (h1 - h0);
        v1 = h1 + wy * (h2 - h1);
        v2 = h2 + wy * (h3 - h2);
        v3 = h3 + wy * (h4 - h3);
    }
    a0 = fmaxf(a0, v0 - k);
    a1 = fmaxf(a1, v1 - k);
    a2 = fmaxf(a2, v2 - k);
    a3 = fmaxf(a3, v3 - k);
}

template<int TH, int... Os>
__device__ __forceinline__ void dil_all(std::integer_sequence<int, Os...>,
        const float* __restrict__ tile, const float* __restrict__ sk, int lb,
        float& a0, float& a1, float& a2, float& a3) {
    (dil_one<TH, Os>(tile, sk, lb, a0, a1, a2, a3), ...);
}

__global__ __launch_bounds__(256) void dil_kernel(
        const float* __restrict__ u, const float* __restrict__ mp,
        float* __restrict__ out) {
    __shared__ float tile[TSZ_];
    __shared__ float s_k[27];

    const int z = blockIdx.z;
    const int c  = z >> 3;
    const int th = z & 7;
    const int t = threadIdx.x;

    if (t < 27) {
        const int hti = t / 9 - 1;
        const int hyi = (t / 3) % 3 - 1;
        const int hxi = t % 3 - 1;
        const float hx = (float)hxi, hy = (float)hyi;
        const float hth  = (float)hti * (2.0f * PI_F / OR_);
        const float half = 0.5f * hth;
        float q;
        if (fabsf(half) < 1e-4f) q = 1.0f - half * half * (1.0f / 3.0f);
        else                     q = half / tanf(half);
        const float c1 = q * hx + half * hy;
        const float c2 = -half * hx + q * hy;
        const float c3 = hth;
        const float m0 = mp[c * 3 + 0], m1 = mp[c * 3 + 1], m2 = mp[c * 3 + 2];
        const float d2 = (m0 * c1) * (m0 * c1) + (m1 * c2) * (m1 * c2) + (m2 * c3) * (m2 * c3);
        const float ee = 2.0f * 0.65f / (2.0f * 0.65f - 1.0f);
        const float nu = (2.0f * 0.65f - 1.0f) * powf(2.0f * 0.65f, -ee);
        s_k[t] = nu * powf(d2, 0.5f * ee);
    }

    // stage 3 planes with halo, zero-padded outside image
    const int bx0 = blockIdx.x * 64 - 2;
    const int by0 = blockIdx.y * 16 - 2;
    const float* __restrict__ base = u + c * CH_;
    for (int i = t; i < TSZ_; i += 256) {
        const int r   = i / TW_;
        const int col = i - r * TW_;
        const int p   = r / TR_;
        const int rr  = r - p * TR_;
        const int gy = by0 + rr;
        const int gx = bx0 + col;
        const int plane = (th + p - 1 + OR_) & 7;
        float v = 0.0f;
        if ((unsigned)gy < (unsigned)H_ && (unsigned)gx < (unsigned)W_)
            v = base[plane * HW_ + gy * W_ + gx];
        tile[i] = v;
    }
    __syncthreads();

    const int tx  = t & 63;
    const int ty0 = (t >> 6) * 4;
    const int lb = (ty0 + 2) * TW_ + tx + 2;

    float a0 = -INFINITY, a1 = -INFINITY, a2 = -INFINITY, a3 = -INFINITY;
    using Seq = std::make_integer_sequence<int, 27>;
    switch (th) {
        case 0: dil_all<0>(Seq{}, tile, s_k, lb, a0, a1, a2, a3); break;
        case 1: dil_all<1>(Seq{}, tile, s_k, lb, a0, a1, a2, a3); break;
        case 2: dil_all<2>(Seq{}, tile, s_k, lb, a0, a1, a2, a3); break;
        case 3: dil_all<3>(Seq{}, tile, s_k, lb, a0, a1, a2, a3); break;
        case 4: dil_all<4>(Seq{}, tile, s_k, lb, a0, a1, a2, a3); break;
        case 5: dil_all<5>(Seq{}, tile, s_k, lb, a0, a1, a2, a3); break;
        case 6: dil_all<6>(Seq{}, tile, s_k, lb, a0, a1, a2, a3); break;
        case 7: dil_all<7>(Seq{}, tile, s_k, lb, a0, a1, a2, a3); break;
        default: __builtin_unreachable();
    }

    const int x = blockIdx.x * 64 + tx;
    const int y = blockIdx.y * 16 + ty0;
    float* __restrict__ op = out + c * CH_ + th * HW_ + y * W_ + x;
    op[0]      = a0;
    op[W_]     = a1;
    op[2 * W_] = a2;
    op[3 * W_] = a3;
}

} // anonymous namespace

extern "C" void kernel_launch(void* const* d_in, const int* in_sizes, int n_in,
                              void* d_out, int out_size, void* d_ws, size_t ws_size,
                              hipStream_t stream) {
    const float* u   = (const float*)d_in[0];
    const float* g0  = (const float*)d_in[1];
    const float* mpp = (const float*)d_in[2];
    float* out = (float*)d_out;
    float* ws  = (float*)d_ws;

    dim3 grid(W_ / 64, H_ / 16, C_ * OR_);
    dim3 block(256);

    conv_kernel<<<grid, block, 0, stream>>>(u,   g0,  ws);
    dil_kernel <<<grid, block, 0, stream>>>(ws,  mpp, out);
    conv_kernel<<<grid, block, 0, stream>>>(out, g0,  ws);
    dil_kernel <<<grid, block, 0, stream>>>(ws,  mpp, out);
}